// Round 11
// baseline (356.039 us; speedup 1.0000x reference)
//
#include <hip/hip_runtime.h>
#include <math.h>

__device__ __forceinline__ float bf2f(unsigned short s) {
    return __uint_as_float(((unsigned)s) << 16);
}
__device__ __forceinline__ unsigned short f2bf(float f) {
    unsigned u = __float_as_uint(f);
    unsigned r = (u + 0x7fffu + ((u >> 16) & 1u)) >> 16;   // RNE
    return (unsigned short)r;
}

typedef __attribute__((ext_vector_type(8))) short short8v;  // 8 bf16 = 4 VGPRs
typedef __attribute__((ext_vector_type(4))) float f32x4;

__device__ __forceinline__ short8v pack8(float4 a, float4 b) {
    short8v r;
    r[0] = (short)f2bf(a.x); r[1] = (short)f2bf(a.y);
    r[2] = (short)f2bf(a.z); r[3] = (short)f2bf(a.w);
    r[4] = (short)f2bf(b.x); r[5] = (short)f2bf(b.y);
    r[6] = (short)f2bf(b.z); r[7] = (short)f2bf(b.w);
    return r;
}

// ================= device bodies (shared by mega kernels) =================

// ---- rank + deg histogram: 8 edges/thread ----
// ~24G scattered device-atomics/s is a HW wall (1-wide, 8-wide ILP, 8x-striped
// all ~52-54us). We hide independent streaming work under it instead.
__device__ __forceinline__ void edge_rank_body(
    int bid, const int* __restrict__ dst, int* __restrict__ cursor,
    int* __restrict__ rank, int E)
{
    int t = bid * 256 + threadIdx.x;
    int base = t * 8;
    if (base >= E) return;
    if (base + 8 <= E) {
        int4 d0 = *(const int4*)(dst + base);
        int4 d1 = *(const int4*)(dst + base + 4);
        int r0 = atomicAdd(&cursor[d0.x], 1);
        int r1 = atomicAdd(&cursor[d0.y], 1);
        int r2 = atomicAdd(&cursor[d0.z], 1);
        int r3 = atomicAdd(&cursor[d0.w], 1);
        int r4 = atomicAdd(&cursor[d1.x], 1);
        int r5 = atomicAdd(&cursor[d1.y], 1);
        int r6 = atomicAdd(&cursor[d1.z], 1);
        int r7 = atomicAdd(&cursor[d1.w], 1);
        *(int4*)(rank + base)     = make_int4(r0, r1, r2, r3);
        *(int4*)(rank + base + 4) = make_int4(r4, r5, r6, r7);
    } else {
        for (int e = base; e < E; ++e)
            rank[e] = atomicAdd(&cursor[dst[e]], 1);
    }
}

// ---- h (fp32) -> hb (bf16), vectorized cast ----
__device__ __forceinline__ void hb_cast_body(
    int bid, const float* __restrict__ h, unsigned short* __restrict__ hb, long total8)
{
    long idx = (long)bid * 256 + threadIdx.x;
    if (idx >= total8) return;
    const float4 a = *(const float4*)(h + idx * 8);
    const float4 b = *(const float4*)(h + idx * 8 + 4);
    union { unsigned short s[8]; uint4 v4; } pk;
    pk.s[0] = f2bf(a.x); pk.s[1] = f2bf(a.y); pk.s[2] = f2bf(a.z); pk.s[3] = f2bf(a.w);
    pk.s[4] = f2bf(b.x); pk.s[5] = f2bf(b.y); pk.s[6] = f2bf(b.z); pk.s[7] = f2bf(b.w);
    *(uint4*)(hb + idx * 8) = pk.v4;
}

// ---- scatter edges into CSR (no atomics, packed 8B) ----
__device__ __forceinline__ void csr_scatter_body(
    int bid, const int* __restrict__ src, const int* __restrict__ dst,
    const float* __restrict__ eig, const int* __restrict__ rank,
    const int* __restrict__ offs, int2* __restrict__ csr, int E)
{
    int e = bid * 256 + threadIdx.x;
    if (e < E) {
        int dn = dst[e];
        int p = offs[dn] + rank[e];
        csr[p] = make_int2(src[e], __float_as_int(eig[e]));
    }
}

// ---- u,v via MFMA; W1 fragments converted fp32->bf16 in-register ----
// out[n,c] = sum_j hb[n,j]*bf16(W1)[c,j]; c<64 -> u, c>=64 -> v (+b1)
// mfma_f32_16x16x32_bf16: A[l&15][(l>>4)*8+j], B[(l>>4)*8+j][l&15],
//                          D: col=l&15 (node), row=(l>>4)*4+r (c).
__device__ __forceinline__ void uv_mfma_body(
    int bid, const unsigned short* __restrict__ hb, const float* __restrict__ W1,
    const float* __restrict__ b1,
    unsigned short* __restrict__ u, unsigned short* __restrict__ v)
{
    int lane = threadIdx.x & 63;
    int wv = threadIdx.x >> 6;          // c-block: c = wv*32 .. wv*32+31
    int lr = lane & 15;
    int lg = lane >> 4;

    // A frags straight from W1 (fp32, L2-hot), converted in-register.
    // bf16(W1)[c][j]: c<64 -> W1[c*128+j] (u rows); c>=64 -> W1[(c-64)*128+64+j] (v rows)
    short8v a[2][2];
#pragma unroll
    for (int rt = 0; rt < 2; ++rt) {
        int c = wv * 32 + rt * 16 + lr;
        const float* wp = (c < 64) ? (W1 + (size_t)c * 128)
                                   : (W1 + (size_t)(c - 64) * 128 + 64);
#pragma unroll
        for (int s = 0; s < 2; ++s) {
            float4 q0 = *(const float4*)(wp + s * 32 + lg * 8);
            float4 q1 = *(const float4*)(wp + s * 32 + lg * 8 + 4);
            a[rt][s] = pack8(q0, q1);
        }
    }

    float b1v[2][4];
#pragma unroll
    for (int rt = 0; rt < 2; ++rt) {
        if (wv >= 2) {
            float4 t4 = *(const float4*)(b1 + (wv - 2) * 32 + rt * 16 + lg * 4);
            b1v[rt][0] = t4.x; b1v[rt][1] = t4.y; b1v[rt][2] = t4.z; b1v[rt][3] = t4.w;
        } else {
            b1v[rt][0] = b1v[rt][1] = b1v[rt][2] = b1v[rt][3] = 0.f;
        }
    }

    unsigned short* outp = (wv < 2) ? u : v;
    int coff0 = (wv & 1) * 32 + lg * 4;

    int n0 = bid * 64;

    short8v bb[2][2];
    {
        const unsigned short* hp = hb + (size_t)(n0 + lr) * 64 + lg * 8;
        bb[0][0] = *(const short8v*)(hp);
        bb[0][1] = *(const short8v*)(hp + 32);
    }
#pragma unroll
    for (int t = 0; t < 4; ++t) {
        int cur = t & 1, nxt = cur ^ 1;
        if (t < 3) {
            const unsigned short* hp = hb + (size_t)(n0 + (t + 1) * 16 + lr) * 64 + lg * 8;
            bb[nxt][0] = *(const short8v*)(hp);
            bb[nxt][1] = *(const short8v*)(hp + 32);
        }
        f32x4 acc0 = {0.f, 0.f, 0.f, 0.f}, acc1 = {0.f, 0.f, 0.f, 0.f};
        acc0 = __builtin_amdgcn_mfma_f32_16x16x32_bf16(a[0][0], bb[cur][0], acc0, 0, 0, 0);
        acc1 = __builtin_amdgcn_mfma_f32_16x16x32_bf16(a[1][0], bb[cur][0], acc1, 0, 0, 0);
        acc0 = __builtin_amdgcn_mfma_f32_16x16x32_bf16(a[0][1], bb[cur][1], acc0, 0, 0, 0);
        acc1 = __builtin_amdgcn_mfma_f32_16x16x32_bf16(a[1][1], bb[cur][1], acc1, 0, 0, 0);
        int node = n0 + t * 16 + lr;
        union { unsigned short s[4]; uint2 v2; } pk;
#pragma unroll
        for (int r = 0; r < 4; ++r) pk.s[r] = f2bf(acc0[r] + b1v[0][r]);
        *(uint2*)(outp + (size_t)node * 64 + coff0) = pk.v2;
#pragma unroll
        for (int r = 0; r < 4; ++r) pk.s[r] = f2bf(acc1[r] + b1v[1][r]);
        *(uint2*)(outp + (size_t)node * 64 + coff0 + 16) = pk.v2;
    }
}

// ================= MEGA kernels: overlap independent stages =================
// MEGA1: edge_rank (atomic wall, machine idle) || hb_cast. Both low-VGPR so
// rank waves keep full occupancy at the wall. Disjoint outputs.
__global__ __launch_bounds__(256) void mega1_kernel(
    const int* __restrict__ dst, int* __restrict__ cursor, int* __restrict__ rank, int E,
    const float* __restrict__ h, unsigned short* __restrict__ hb, long total8,
    int nrank)
{
    int b = blockIdx.x;
    if (b < nrank) edge_rank_body(b, dst, cursor, rank, E);
    else           hb_cast_body(b - nrank, h, hb, total8);
}

// MEGA2: uv_mfma (MFMA-bound) || csr_scatter (sector-write-bound).
__global__ __launch_bounds__(256) void mega2_kernel(
    const unsigned short* __restrict__ hb, const float* __restrict__ W1,
    const float* __restrict__ b1, unsigned short* __restrict__ u, unsigned short* __restrict__ v,
    const int* __restrict__ src, const int* __restrict__ dst, const float* __restrict__ eig,
    const int* __restrict__ rank, const int* __restrict__ offs, int2* __restrict__ csr,
    int E, int nuv)
{
    int b = blockIdx.x;
    if (b < nuv) uv_mfma_body(b, hb, W1, b1, u, v);
    else         csr_scatter_body(b - nuv, src, dst, eig, rank, offs, csr, E);
}

// ---------------- K2a: per-block reduce of deg ----------------
__global__ __launch_bounds__(256) void block_reduce_kernel(
    const int* __restrict__ deg, int* __restrict__ bsum, int N)
{
    __shared__ int sd[256];
    int t = threadIdx.x;
    int i = blockIdx.x * 256 + t;
    sd[t] = (i < N) ? deg[i] : 0;
    __syncthreads();
    for (int s = 128; s > 0; s >>= 1) {
        if (t < s) sd[t] += sd[t + s];
        __syncthreads();
    }
    if (t == 0) bsum[blockIdx.x] = sd[0];
}

// ---------------- K2b: scan block sums (single block) ----------------
__global__ __launch_bounds__(1024) void scan_bsums_kernel(
    const int* __restrict__ bsum, int* __restrict__ bscan, int nb)
{
    __shared__ int sd[1024];
    int t = threadIdx.x;
    int own = (t < nb) ? bsum[t] : 0;
    sd[t] = own;
    __syncthreads();
    for (int off = 1; off < 1024; off <<= 1) {
        int v = (t >= off) ? sd[t - off] : 0;
        __syncthreads();
        sd[t] += v;
        __syncthreads();
    }
    if (t < nb) bscan[t] = sd[t] - own;   // exclusive prefix
}

// ---------------- K2c: per-block exclusive scan -> offsets ----------------
__global__ __launch_bounds__(256) void block_scan_kernel(
    const int* __restrict__ deg, const int* __restrict__ bscan,
    int* __restrict__ offs, int N)
{
    __shared__ int sd[256];
    int t = threadIdx.x;
    int i = blockIdx.x * 256 + t;
    int myv = (i < N) ? deg[i] : 0;
    sd[t] = myv;
    __syncthreads();
    for (int off = 1; off < 256; off <<= 1) {
        int v = (t >= off) ? sd[t - off] : 0;
        __syncthreads();
        sd[t] += v;
        __syncthreads();
    }
    if (i < N) {
        offs[i] = sd[t] - myv + bscan[blockIdx.x];
    }
}

// ---------------- K5: aggregation, one wave per node (scalar edge records, 8-wide) ----------------
__global__ __launch_bounds__(256) void agg_kernel(
    const unsigned short* __restrict__ u, const unsigned short* __restrict__ v,
    const unsigned short* __restrict__ hb,
    const int* __restrict__ offs, const int* __restrict__ degi,
    const int2* __restrict__ csr,
    unsigned short* __restrict__ agg, int N)
{
    int gw = (blockIdx.x * 256 + threadIdx.x) >> 6;
    int lane = threadIdx.x & 63;
    int n = __builtin_amdgcn_readfirstlane(gw);
    if (n >= N) return;
    int dn  = __builtin_amdgcn_readfirstlane(degi[n]);
    int beg = __builtin_amdgcn_readfirstlane(offs[n]);

    float vl = bf2f(v[(size_t)n * 64 + lane]);
    float hl = bf2f(hb[(size_t)n * 64 + lane]);

    const int2* ep = csr + beg;
    float accs = 0.f, accd = 0.f, accm = -3.402823466e38f;
    float pa = 0.f, ps = 0.f;

    int j = 0;
    for (; j + 8 <= dn; j += 8) {   // 8 gathers in flight
        int2 r0 = ep[j],     r1 = ep[j + 1], r2 = ep[j + 2], r3 = ep[j + 3];
        int2 r4 = ep[j + 4], r5 = ep[j + 5], r6 = ep[j + 6], r7 = ep[j + 7];
        float u0 = bf2f(u[(size_t)r0.x * 64 + lane]);
        float u1 = bf2f(u[(size_t)r1.x * 64 + lane]);
        float u2 = bf2f(u[(size_t)r2.x * 64 + lane]);
        float u3 = bf2f(u[(size_t)r3.x * 64 + lane]);
        float u4 = bf2f(u[(size_t)r4.x * 64 + lane]);
        float u5 = bf2f(u[(size_t)r5.x * 64 + lane]);
        float u6 = bf2f(u[(size_t)r6.x * 64 + lane]);
        float u7 = bf2f(u[(size_t)r7.x * 64 + lane]);
        float w0 = __int_as_float(r0.y), w1 = __int_as_float(r1.y);
        float w2_ = __int_as_float(r2.y), w3 = __int_as_float(r3.y);
        float w4 = __int_as_float(r4.y), w5 = __int_as_float(r5.y);
        float w6 = __int_as_float(r6.y), w7 = __int_as_float(r7.y);
        pa += ((fabsf(w0) + fabsf(w1)) + (fabsf(w2_) + fabsf(w3)))
            + ((fabsf(w4) + fabsf(w5)) + (fabsf(w6) + fabsf(w7)));
        ps += ((w0 + w1) + (w2_ + w3)) + ((w4 + w5) + (w6 + w7));
        accs += ((u0 + u1) + (u2 + u3)) + ((u4 + u5) + (u6 + u7));
        accm = fmaxf(accm, fmaxf(fmaxf(fmaxf(u0, u1), fmaxf(u2, u3)),
                                 fmaxf(fmaxf(u4, u5), fmaxf(u6, u7))));
        accd = fmaf(w0, u0, fmaf(w1, u1, fmaf(w2_, u2, fmaf(w3, u3, accd))));
        accd = fmaf(w4, u4, fmaf(w5, u5, fmaf(w6, u6, fmaf(w7, u7, accd))));
    }
    for (; j + 4 <= dn; j += 4) {
        int2 r0 = ep[j], r1 = ep[j + 1], r2 = ep[j + 2], r3 = ep[j + 3];
        float u0 = bf2f(u[(size_t)r0.x * 64 + lane]);
        float u1 = bf2f(u[(size_t)r1.x * 64 + lane]);
        float u2 = bf2f(u[(size_t)r2.x * 64 + lane]);
        float u3 = bf2f(u[(size_t)r3.x * 64 + lane]);
        float w0 = __int_as_float(r0.y), w1 = __int_as_float(r1.y);
        float w2_ = __int_as_float(r2.y), w3 = __int_as_float(r3.y);
        pa += (fabsf(w0) + fabsf(w1)) + (fabsf(w2_) + fabsf(w3));
        ps += (w0 + w1) + (w2_ + w3);
        accs += (u0 + u1) + (u2 + u3);
        accm = fmaxf(accm, fmaxf(fmaxf(u0, u1), fmaxf(u2, u3)));
        accd = fmaf(w0, u0, fmaf(w1, u1, fmaf(w2_, u2, fmaf(w3, u3, accd))));
    }
    for (; j < dn; ++j) {
        int2 r0 = ep[j];
        float u0 = bf2f(u[(size_t)r0.x * 64 + lane]);
        float w0 = __int_as_float(r0.y);
        pa += fabsf(w0);
        ps += w0;
        accs += u0;
        accm = fmaxf(accm, u0);
        accd = fmaf(w0, u0, accd);
    }

    float inv_ab = 1.f / (pa + 1e-8f);
    float segw = ps * inv_ab;

    float fdeg = (float)dn;
    float mean = (accs + fdeg * vl) / fmaxf(fdeg, 1.f);
    float amax = (dn > 0) ? (accm + vl) : 0.f;
    float adir = fabsf(fmaf(accd, inv_ab, segw * (vl - hl)));
    size_t base = (size_t)n * 192;
    agg[base + lane]       = f2bf(mean);
    agg[base + 64 + lane]  = f2bf(amax);
    agg[base + 128 + lane] = f2bf(adir);
}

// ---------------- K6: posttrans via MFMA + per-block BN partials ----------------
// 64 nodes/block (4 tiles) -> 1563 blocks: more TLP for the load->MFMA chain
// (atomic epilogue is gone, so small blocks no longer pay a contention tax).
// W2 fragments converted fp32->bf16 in-register (W2 is 64KB, L2-hot).
__global__ __launch_bounds__(256) void post_mfma_kernel(
    const unsigned short* __restrict__ hb, const unsigned short* __restrict__ agg,
    const float* __restrict__ W2, const float* __restrict__ b2,
    const float* __restrict__ snorm, float* __restrict__ h2,
    float* __restrict__ bn_part, int N)
{
    int lane = threadIdx.x & 63;
    int w = threadIdx.x >> 6;
    int lr = lane & 15;
    int lg = lane >> 4;

    short8v a[8];
    {
        int d = w * 16 + lr;
        const float* wp = W2 + (size_t)d * 256 + lg * 8;
#pragma unroll
        for (int s = 0; s < 8; ++s) {
            float4 q0 = *(const float4*)(wp + s * 32);
            float4 q1 = *(const float4*)(wp + s * 32 + 4);
            a[s] = pack8(q0, q1);
        }
    }
    float4 b2v = *(const float4*)(b2 + w * 16 + lg * 4);
    float b2a[4] = {b2v.x, b2v.y, b2v.z, b2v.w};

    int n0 = blockIdx.x * 64;
    float s1[4] = {0.f, 0.f, 0.f, 0.f}, s2[4] = {0.f, 0.f, 0.f, 0.f};

    short8v bb[2][8];
    float snv[2];

#define LOADT(BUF, T)                                                            \
    {                                                                            \
        int node_ = n0 + (T) * 16 + lr;                                          \
        const unsigned short* hbp_ = hb  + (size_t)node_ * 64  + lg * 8;         \
        const unsigned short* agp_ = agg + (size_t)node_ * 192 + lg * 8;         \
        bb[BUF][0] = *(const short8v*)(hbp_);                                    \
        bb[BUF][1] = *(const short8v*)(hbp_ + 32);                               \
        bb[BUF][2] = *(const short8v*)(agp_);                                    \
        bb[BUF][3] = *(const short8v*)(agp_ + 32);                               \
        bb[BUF][4] = *(const short8v*)(agp_ + 64);                               \
        bb[BUF][5] = *(const short8v*)(agp_ + 96);                               \
        bb[BUF][6] = *(const short8v*)(agp_ + 128);                              \
        bb[BUF][7] = *(const short8v*)(agp_ + 160);                              \
        int nc_ = (node_ < N) ? node_ : (N - 1);                                 \
        snv[BUF] = snorm[nc_];                                                   \
    }

    LOADT(0, 0)
#pragma unroll
    for (int t = 0; t < 4; ++t) {
        int cur = t & 1, nxt = cur ^ 1;
        if (t < 3) LOADT(nxt, t + 1)
        f32x4 acc0 = {0.f, 0.f, 0.f, 0.f}, acc1 = {0.f, 0.f, 0.f, 0.f};
#pragma unroll
        for (int s = 0; s < 8; s += 2) {
            acc0 = __builtin_amdgcn_mfma_f32_16x16x32_bf16(a[s],     bb[cur][s],     acc0, 0, 0, 0);
            acc1 = __builtin_amdgcn_mfma_f32_16x16x32_bf16(a[s + 1], bb[cur][s + 1], acc1, 0, 0, 0);
        }
        int node = n0 + t * 16 + lr;
        bool ok = node < N;
        float sn = snv[cur];
        float xr[4];
#pragma unroll
        for (int r = 0; r < 4; ++r) {
            float val = (acc0[r] + acc1[r] + b2a[r]) * sn;
            val = ok ? val : 0.f;
            xr[r] = val;
            s1[r] += val;
            s2[r] = fmaf(val, val, s2[r]);
        }
        *(float4*)(h2 + (size_t)node * 64 + w * 16 + lg * 4) =
            make_float4(xr[0], xr[1], xr[2], xr[3]);
    }
#undef LOADT

#pragma unroll
    for (int m = 1; m < 16; m <<= 1) {
#pragma unroll
        for (int r = 0; r < 4; ++r) {
            s1[r] += __shfl_xor(s1[r], m);
            s2[r] += __shfl_xor(s2[r], m);
        }
    }
    if (lr == 0) {
        int d = w * 16 + lg * 4;
        float* bp = bn_part + (size_t)blockIdx.x * 128;
#pragma unroll
        for (int r = 0; r < 4; ++r) {
            bp[d + r]      = s1[r];
            bp[64 + d + r] = s2[r];
        }
    }
}

// ---------------- K6b: parallel reduce of BN partials -> scale/bias ----------------
__global__ __launch_bounds__(1024) void bn_reduce_kernel(
    const float* __restrict__ bn_part, const float* __restrict__ gamma,
    const float* __restrict__ beta, float* __restrict__ bn_buf, int nblk, float invN)
{
    __shared__ float sred[1024];
    int t = threadIdx.x;
    int d = t & 127;
    int sl = t >> 7;
    float s = 0.f;
    for (int b = sl; b < nblk; b += 8)
        s += bn_part[(size_t)b * 128 + d];
    sred[t] = s;
    __syncthreads();
    if (sl == 0) {
        float tot = s;
#pragma unroll
        for (int k = 1; k < 8; ++k) tot += sred[k * 128 + d];
        sred[d] = tot;
    }
    __syncthreads();
    if (t < 64) {
        float s1 = sred[t], s2 = sred[64 + t];
        float mu = s1 * invN;
        float var = s2 * invN - mu * mu;
        float rstd = rsqrtf(var + 1e-5f);
        float sc = rstd * gamma[t];
        bn_buf[t]      = sc;
        bn_buf[64 + t] = beta[t] - mu * sc;
    }
}

// ---------------- K7: BN normalize + relu + residual ----------------
__global__ __launch_bounds__(256) void bn_final_kernel(
    const float* __restrict__ h, const float* __restrict__ h2,
    const float* __restrict__ bn_buf, float* __restrict__ out, int N)
{
    int idx = blockIdx.x * 256 + threadIdx.x;
    int total4 = N * 16;
    if (idx >= total4) return;
    int base = idx * 4;
    int d0 = base & 63;
    const float4 a = *(const float4*)(h2 + base);
    const float4 hh = *(const float4*)(h + base);
    float r[4] = {a.x, a.y, a.z, a.w};
    float hv[4] = {hh.x, hh.y, hh.z, hh.w};
    float o[4];
#pragma unroll
    for (int k = 0; k < 4; ++k) {
        int d = d0 + k;
        float x = fmaf(r[k], bn_buf[d], bn_buf[64 + d]);
        o[k] = hv[k] + fmaxf(x, 0.f);
    }
    float4 ov = {o[0], o[1], o[2], o[3]};
    *(float4*)(out + base) = ov;
}

// ---------------- launch ----------------
extern "C" void kernel_launch(void* const* d_in, const int* in_sizes, int n_in,
                              void* d_out, int out_size, void* d_ws, size_t ws_size,
                              hipStream_t stream)
{
    const float* h     = (const float*)d_in[0];
    const float* eig   = (const float*)d_in[1];
    const float* snorm = (const float*)d_in[2];
    const int*   src   = (const int*)d_in[3];
    const int*   dst   = (const int*)d_in[4];
    const float* W1    = (const float*)d_in[5];
    const float* b1    = (const float*)d_in[6];
    const float* W2    = (const float*)d_in[7];
    const float* b2    = (const float*)d_in[8];
    const float* gamma = (const float*)d_in[9];
    const float* beta  = (const float*)d_in[10];
    float* out = (float*)d_out;

    const int N = in_sizes[2];
    const int E = in_sizes[1];
    const int Npad = (N + 255) & ~255;   // padded rows: branchless MFMA kernels
    const int pblk = (N + 63) / 64;      // post_mfma grid (64 nodes/block)

    // ---- workspace layout (256B aligned slices) ----
    char* w = (char*)d_ws;
    size_t off = 0;
    auto alloc = [&](size_t bytes) -> char* {
        char* p = w + off;
        off += (bytes + 255) & ~size_t(255);
        return p;
    };
    unsigned short* u = (unsigned short*)alloc((size_t)Npad * 64 * 2);
    unsigned short* v = (unsigned short*)alloc((size_t)Npad * 64 * 2);
    float* h2 = (float*)u;   // alias: u,v dead after agg_kernel
    unsigned short* agg = (unsigned short*)alloc((size_t)Npad * 192 * 2);
    unsigned short* hb  = (unsigned short*)alloc((size_t)Npad * 64 * 2);
    int2* csr = (int2*)alloc((size_t)E * 8);
    int*  rank = (int*)alloc((size_t)E * 4);
    // zero region: cursor (deg histogram) only
    char* zero_base = w + off;
    int*   cursor = (int*)alloc((size_t)N * 4);   // becomes deg
    size_t zero_bytes = (size_t)((w + off) - zero_base);
    float* bn_part = (float*)alloc((size_t)pblk * 128 * 4);
    float* bn_buf  = (float*)alloc(128 * 4);
    int* offs = (int*)alloc((size_t)N * 4);
    int nb = (N + 255) / 256;
    int* bsum  = (int*)alloc((size_t)nb * 4);
    int* bscan = (int*)alloc((size_t)nb * 4);
    (void)ws_size; (void)n_in; (void)out_size;

    hipMemsetAsync(zero_base, 0, zero_bytes, stream);

    // MEGA1: edge_rank (atomic wall) || hb_cast
    long total8 = (long)N * 8;
    int nrank = (E + 2047) / 2048;                  // 8 edges/thread
    int ncast = (int)((total8 + 255) / 256);
    mega1_kernel<<<nrank + ncast, 256, 0, stream>>>(
        dst, cursor, rank, E, h, hb, total8, nrank);

    block_reduce_kernel<<<nb, 256, 0, stream>>>(cursor, bsum, N);
    scan_bsums_kernel<<<1, 1024, 0, stream>>>(bsum, bscan, nb);
    block_scan_kernel<<<nb, 256, 0, stream>>>(cursor, bscan, offs, N);

    // MEGA2: uv_mfma || csr_scatter
    int nuv = (N + 63) / 64;
    int nscat = (E + 255) / 256;
    mega2_kernel<<<nuv + nscat, 256, 0, stream>>>(
        hb, W1, b1, u, v, src, dst, eig, rank, offs, csr, E, nuv);

    int agrid = (int)(((size_t)N * 64 + 255) / 256);
    agg_kernel<<<agrid, 256, 0, stream>>>(u, v, hb, offs, cursor, csr, agg, N);

    post_mfma_kernel<<<pblk, 256, 0, stream>>>(hb, agg, W2, b2, snorm,
                                               h2, bn_part, N);

    bn_reduce_kernel<<<1, 1024, 0, stream>>>(bn_part, gamma, beta, bn_buf, pblk, 1.0f / (float)N);

    int fgrid = (N * 16 + 255) / 256;
    bn_final_kernel<<<fgrid, 256, 0, stream>>>(h, h2, bn_buf, out, N);
}

// Round 12
// 320.303 us; speedup vs baseline: 1.1116x; 1.1116x over previous
//
#include <hip/hip_runtime.h>
#include <math.h>

__device__ __forceinline__ float bf2f(unsigned short s) {
    return __uint_as_float(((unsigned)s) << 16);
}
__device__ __forceinline__ unsigned short f2bf(float f) {
    unsigned u = __float_as_uint(f);
    unsigned r = (u + 0x7fffu + ((u >> 16) & 1u)) >> 16;   // RNE
    return (unsigned short)r;
}

typedef __attribute__((ext_vector_type(8))) short short8v;  // 8 bf16 = 4 VGPRs
typedef __attribute__((ext_vector_type(4))) float f32x4;

// ================= device bodies (shared by mega kernels) =================

// ---- rank + deg histogram: 8 edges/thread, 8 atomic-returns in flight ----
// ~24G scattered device-atomics/s is a HW wall (1-wide, 8-wide ILP, 8x-striped
// all ~52-54us). We hide independent streaming work under it instead.
__device__ __forceinline__ void edge_rank_body(
    int bid, const int* __restrict__ dst, int* __restrict__ cursor,
    int* __restrict__ rank, int E)
{
    int t = bid * 256 + threadIdx.x;
    int base = t * 8;
    if (base >= E) return;
    if (base + 8 <= E) {
        int4 d0 = *(const int4*)(dst + base);
        int4 d1 = *(const int4*)(dst + base + 4);
        int r0 = atomicAdd(&cursor[d0.x], 1);
        int r1 = atomicAdd(&cursor[d0.y], 1);
        int r2 = atomicAdd(&cursor[d0.z], 1);
        int r3 = atomicAdd(&cursor[d0.w], 1);
        int r4 = atomicAdd(&cursor[d1.x], 1);
        int r5 = atomicAdd(&cursor[d1.y], 1);
        int r6 = atomicAdd(&cursor[d1.z], 1);
        int r7 = atomicAdd(&cursor[d1.w], 1);
        *(int4*)(rank + base)     = make_int4(r0, r1, r2, r3);
        *(int4*)(rank + base + 4) = make_int4(r4, r5, r6, r7);
    } else {
        for (int e = base; e < E; ++e)
            rank[e] = atomicAdd(&cursor[dst[e]], 1);
    }
}

// ---- h (fp32) -> hb (bf16), vectorized cast ----
__device__ __forceinline__ void hb_cast_body(
    int bid, const float* __restrict__ h, unsigned short* __restrict__ hb, long total8)
{
    long idx = (long)bid * 256 + threadIdx.x;
    if (idx >= total8) return;
    const float4 a = *(const float4*)(h + idx * 8);
    const float4 b = *(const float4*)(h + idx * 8 + 4);
    union { unsigned short s[8]; uint4 v4; } pk;
    pk.s[0] = f2bf(a.x); pk.s[1] = f2bf(a.y); pk.s[2] = f2bf(a.z); pk.s[3] = f2bf(a.w);
    pk.s[4] = f2bf(b.x); pk.s[5] = f2bf(b.y); pk.s[6] = f2bf(b.z); pk.s[7] = f2bf(b.w);
    *(uint4*)(hb + idx * 8) = pk.v4;
}

// ---- weight prep -> bf16 (tiny; rides MEGA1 tail) ----
// w1bf[c][j], c in 0..127: c<64 -> W1[c][j] (u rows); c>=64 -> W1[c-64][64+j] (v rows)
// w2bf = bf16(W2) in original [64][256] layout
__device__ __forceinline__ void wprep_body(
    int bid, const float* __restrict__ W1, const float* __restrict__ W2,
    unsigned short* __restrict__ w1bf, unsigned short* __restrict__ w2bf)
{
    int idx = bid * 256 + threadIdx.x;
    if (idx < 128 * 64) {
        int c = idx >> 6, j = idx & 63;
        float val = (c < 64) ? W1[c * 128 + j] : W1[(c - 64) * 128 + 64 + j];
        w1bf[idx] = f2bf(val);
    } else if (idx < 128 * 64 + 64 * 256) {
        int k = idx - 128 * 64;
        w2bf[k] = f2bf(W2[k]);
    }
}

// ---- scatter edges into CSR (no atomics, packed 8B) ----
__device__ __forceinline__ void csr_scatter_body(
    int bid, const int* __restrict__ src, const int* __restrict__ dst,
    const float* __restrict__ eig, const int* __restrict__ rank,
    const int* __restrict__ offs, int2* __restrict__ csr, int E)
{
    int e = bid * 256 + threadIdx.x;
    if (e < E) {
        int dn = dst[e];
        int p = offs[dn] + rank[e];
        csr[p] = make_int2(src[e], __float_as_int(eig[e]));
    }
}

// ---- u,v via MFMA (branchless, prefetch double-buffer) ----
// out[n,c] = sum_j hb[n,j]*w1bf[c,j]; c<64 -> u, c>=64 -> v (+b1)
// mfma_f32_16x16x32_bf16: A[l&15][(l>>4)*8+j], B[(l>>4)*8+j][l&15],
//                          D: col=l&15 (node), row=(l>>4)*4+r (c).
__device__ __forceinline__ void uv_mfma_body(
    int bid, const unsigned short* __restrict__ hb, const unsigned short* __restrict__ w1bf,
    const float* __restrict__ b1,
    unsigned short* __restrict__ u, unsigned short* __restrict__ v)
{
    int lane = threadIdx.x & 63;
    int wv = threadIdx.x >> 6;          // c-block: c = wv*32 .. wv*32+31
    int lr = lane & 15;
    int lg = lane >> 4;

    short8v a[2][2];
#pragma unroll
    for (int rt = 0; rt < 2; ++rt)
#pragma unroll
        for (int s = 0; s < 2; ++s)
            a[rt][s] = *(const short8v*)(w1bf + (size_t)(wv * 32 + rt * 16 + lr) * 64 + s * 32 + lg * 8);

    float b1v[2][4];
#pragma unroll
    for (int rt = 0; rt < 2; ++rt) {
        if (wv >= 2) {
            float4 t4 = *(const float4*)(b1 + (wv - 2) * 32 + rt * 16 + lg * 4);
            b1v[rt][0] = t4.x; b1v[rt][1] = t4.y; b1v[rt][2] = t4.z; b1v[rt][3] = t4.w;
        } else {
            b1v[rt][0] = b1v[rt][1] = b1v[rt][2] = b1v[rt][3] = 0.f;
        }
    }

    unsigned short* outp = (wv < 2) ? u : v;
    int coff0 = (wv & 1) * 32 + lg * 4;

    int n0 = bid * 64;

    short8v bb[2][2];
    {
        const unsigned short* hp = hb + (size_t)(n0 + lr) * 64 + lg * 8;
        bb[0][0] = *(const short8v*)(hp);
        bb[0][1] = *(const short8v*)(hp + 32);
    }
#pragma unroll
    for (int t = 0; t < 4; ++t) {
        int cur = t & 1, nxt = cur ^ 1;
        if (t < 3) {
            const unsigned short* hp = hb + (size_t)(n0 + (t + 1) * 16 + lr) * 64 + lg * 8;
            bb[nxt][0] = *(const short8v*)(hp);
            bb[nxt][1] = *(const short8v*)(hp + 32);
        }
        f32x4 acc0 = {0.f, 0.f, 0.f, 0.f}, acc1 = {0.f, 0.f, 0.f, 0.f};
        acc0 = __builtin_amdgcn_mfma_f32_16x16x32_bf16(a[0][0], bb[cur][0], acc0, 0, 0, 0);
        acc1 = __builtin_amdgcn_mfma_f32_16x16x32_bf16(a[1][0], bb[cur][0], acc1, 0, 0, 0);
        acc0 = __builtin_amdgcn_mfma_f32_16x16x32_bf16(a[0][1], bb[cur][1], acc0, 0, 0, 0);
        acc1 = __builtin_amdgcn_mfma_f32_16x16x32_bf16(a[1][1], bb[cur][1], acc1, 0, 0, 0);
        int node = n0 + t * 16 + lr;
        union { unsigned short s[4]; uint2 v2; } pk;
#pragma unroll
        for (int r = 0; r < 4; ++r) pk.s[r] = f2bf(acc0[r] + b1v[0][r]);
        *(uint2*)(outp + (size_t)node * 64 + coff0) = pk.v2;
#pragma unroll
        for (int r = 0; r < 4; ++r) pk.s[r] = f2bf(acc1[r] + b1v[1][r]);
        *(uint2*)(outp + (size_t)node * 64 + coff0 + 16) = pk.v2;
    }
}

// ================= MEGA kernels: overlap independent stages =================
// MEGA1: edge_rank (atomic wall, machine idle) || hb_cast || wprep.
// Disjoint outputs -> trivially correct; streaming work rides the idle BW/VALU.
__global__ __launch_bounds__(256) void mega1_kernel(
    const int* __restrict__ dst, int* __restrict__ cursor, int* __restrict__ rank, int E,
    const float* __restrict__ h, unsigned short* __restrict__ hb, long total8,
    const float* __restrict__ W1, const float* __restrict__ W2,
    unsigned short* __restrict__ w1bf, unsigned short* __restrict__ w2bf,
    int nrank, int ncast)
{
    int b = blockIdx.x;
    if (b < nrank)              edge_rank_body(b, dst, cursor, rank, E);
    else if (b < nrank + ncast) hb_cast_body(b - nrank, h, hb, total8);
    else                        wprep_body(b - nrank - ncast, W1, W2, w1bf, w2bf);
}

// MEGA2: uv_mfma (MFMA-bound) || csr_scatter (sector-write-bound).
// uv blocks first so matrix work launches immediately under the scatter.
__global__ __launch_bounds__(256) void mega2_kernel(
    const unsigned short* __restrict__ hb, const unsigned short* __restrict__ w1bf,
    const float* __restrict__ b1, unsigned short* __restrict__ u, unsigned short* __restrict__ v,
    const int* __restrict__ src, const int* __restrict__ dst, const float* __restrict__ eig,
    const int* __restrict__ rank, const int* __restrict__ offs, int2* __restrict__ csr,
    int E, int nuv)
{
    int b = blockIdx.x;
    if (b < nuv) uv_mfma_body(b, hb, w1bf, b1, u, v);
    else         csr_scatter_body(b - nuv, src, dst, eig, rank, offs, csr, E);
}

// ---------------- K2a: per-block reduce of deg ----------------
__global__ __launch_bounds__(256) void block_reduce_kernel(
    const int* __restrict__ deg, int* __restrict__ bsum, int N)
{
    __shared__ int sd[256];
    int t = threadIdx.x;
    int i = blockIdx.x * 256 + t;
    sd[t] = (i < N) ? deg[i] : 0;
    __syncthreads();
    for (int s = 128; s > 0; s >>= 1) {
        if (t < s) sd[t] += sd[t + s];
        __syncthreads();
    }
    if (t == 0) bsum[blockIdx.x] = sd[0];
}

// ---------------- K2b: scan block sums (single block) ----------------
__global__ __launch_bounds__(1024) void scan_bsums_kernel(
    const int* __restrict__ bsum, int* __restrict__ bscan, int nb)
{
    __shared__ int sd[1024];
    int t = threadIdx.x;
    int own = (t < nb) ? bsum[t] : 0;
    sd[t] = own;
    __syncthreads();
    for (int off = 1; off < 1024; off <<= 1) {
        int v = (t >= off) ? sd[t - off] : 0;
        __syncthreads();
        sd[t] += v;
        __syncthreads();
    }
    if (t < nb) bscan[t] = sd[t] - own;   // exclusive prefix
}

// ---------------- K2c: per-block exclusive scan -> offsets ----------------
__global__ __launch_bounds__(256) void block_scan_kernel(
    const int* __restrict__ deg, const int* __restrict__ bscan,
    int* __restrict__ offs, int N)
{
    __shared__ int sd[256];
    int t = threadIdx.x;
    int i = blockIdx.x * 256 + t;
    int myv = (i < N) ? deg[i] : 0;
    sd[t] = myv;
    __syncthreads();
    for (int off = 1; off < 256; off <<= 1) {
        int v = (t >= off) ? sd[t - off] : 0;
        __syncthreads();
        sd[t] += v;
        __syncthreads();
    }
    if (i < N) {
        offs[i] = sd[t] - myv + bscan[blockIdx.x];
    }
}

// ---------------- K5: aggregation, one wave per node (scalar edge records) ----------------
__global__ __launch_bounds__(256) void agg_kernel(
    const unsigned short* __restrict__ u, const unsigned short* __restrict__ v,
    const unsigned short* __restrict__ hb,
    const int* __restrict__ offs, const int* __restrict__ degi,
    const int2* __restrict__ csr,
    unsigned short* __restrict__ agg, int N)
{
    int gw = (blockIdx.x * 256 + threadIdx.x) >> 6;
    int lane = threadIdx.x & 63;
    int n = __builtin_amdgcn_readfirstlane(gw);
    if (n >= N) return;
    int dn  = __builtin_amdgcn_readfirstlane(degi[n]);
    int beg = __builtin_amdgcn_readfirstlane(offs[n]);

    float vl = bf2f(v[(size_t)n * 64 + lane]);
    float hl = bf2f(hb[(size_t)n * 64 + lane]);

    const int2* ep = csr + beg;
    float accs = 0.f, accd = 0.f, accm = -3.402823466e38f;
    float pa = 0.f, ps = 0.f;

    int j = 0;
    for (; j + 4 <= dn; j += 4) {
        int2 r0 = ep[j], r1 = ep[j + 1], r2 = ep[j + 2], r3 = ep[j + 3];
        float u0 = bf2f(u[(size_t)r0.x * 64 + lane]);
        float u1 = bf2f(u[(size_t)r1.x * 64 + lane]);
        float u2 = bf2f(u[(size_t)r2.x * 64 + lane]);
        float u3 = bf2f(u[(size_t)r3.x * 64 + lane]);
        float w0 = __int_as_float(r0.y), w1 = __int_as_float(r1.y);
        float w2_ = __int_as_float(r2.y), w3 = __int_as_float(r3.y);
        pa += (fabsf(w0) + fabsf(w1)) + (fabsf(w2_) + fabsf(w3));
        ps += (w0 + w1) + (w2_ + w3);
        accs += (u0 + u1) + (u2 + u3);
        accm = fmaxf(accm, fmaxf(fmaxf(u0, u1), fmaxf(u2, u3)));
        accd = fmaf(w0, u0, fmaf(w1, u1, fmaf(w2_, u2, fmaf(w3, u3, accd))));
    }
    for (; j < dn; ++j) {
        int2 r0 = ep[j];
        float u0 = bf2f(u[(size_t)r0.x * 64 + lane]);
        float w0 = __int_as_float(r0.y);
        pa += fabsf(w0);
        ps += w0;
        accs += u0;
        accm = fmaxf(accm, u0);
        accd = fmaf(w0, u0, accd);
    }

    float inv_ab = 1.f / (pa + 1e-8f);
    float segw = ps * inv_ab;

    float fdeg = (float)dn;
    float mean = (accs + fdeg * vl) / fmaxf(fdeg, 1.f);
    float amax = (dn > 0) ? (accm + vl) : 0.f;
    float adir = fabsf(fmaf(accd, inv_ab, segw * (vl - hl)));
    size_t base = (size_t)n * 192;
    agg[base + lane]       = f2bf(mean);
    agg[base + 64 + lane]  = f2bf(amax);
    agg[base + 128 + lane] = f2bf(adir);
}

// ---------------- K6: posttrans via MFMA + per-block BN partials (NO atomics) ----------------
// 128 nodes/block (8 tiles), 4 waves split over d; bf16 w2bf (L2-hot, minimal bytes).
__global__ __launch_bounds__(256) void post_mfma_kernel(
    const unsigned short* __restrict__ hb, const unsigned short* __restrict__ agg,
    const unsigned short* __restrict__ w2bf, const float* __restrict__ b2,
    const float* __restrict__ snorm, float* __restrict__ h2,
    float* __restrict__ bn_part, int N)
{
    int lane = threadIdx.x & 63;
    int w = threadIdx.x >> 6;
    int lr = lane & 15;
    int lg = lane >> 4;

    short8v a[8];
    {
        const unsigned short* ab = w2bf + ((size_t)(w * 16 + lr)) * 256 + lg * 8;
#pragma unroll
        for (int s = 0; s < 8; ++s)
            a[s] = *(const short8v*)(ab + s * 32);
    }
    float4 b2v = *(const float4*)(b2 + w * 16 + lg * 4);
    float b2a[4] = {b2v.x, b2v.y, b2v.z, b2v.w};

    int n0 = blockIdx.x * 128;
    float s1[4] = {0.f, 0.f, 0.f, 0.f}, s2[4] = {0.f, 0.f, 0.f, 0.f};

    short8v bb[2][8];
    float snv[2];

#define LOADT(BUF, T)                                                            \
    {                                                                            \
        int node_ = n0 + (T) * 16 + lr;                                          \
        const unsigned short* hbp_ = hb  + (size_t)node_ * 64  + lg * 8;         \
        const unsigned short* agp_ = agg + (size_t)node_ * 192 + lg * 8;         \
        bb[BUF][0] = *(const short8v*)(hbp_);                                    \
        bb[BUF][1] = *(const short8v*)(hbp_ + 32);                               \
        bb[BUF][2] = *(const short8v*)(agp_);                                    \
        bb[BUF][3] = *(const short8v*)(agp_ + 32);                               \
        bb[BUF][4] = *(const short8v*)(agp_ + 64);                               \
        bb[BUF][5] = *(const short8v*)(agp_ + 96);                               \
        bb[BUF][6] = *(const short8v*)(agp_ + 128);                              \
        bb[BUF][7] = *(const short8v*)(agp_ + 160);                              \
        int nc_ = (node_ < N) ? node_ : (N - 1);                                 \
        snv[BUF] = snorm[nc_];                                                   \
    }

    LOADT(0, 0)
#pragma unroll
    for (int t = 0; t < 8; ++t) {
        int cur = t & 1, nxt = cur ^ 1;
        if (t < 7) LOADT(nxt, t + 1)
        f32x4 acc0 = {0.f, 0.f, 0.f, 0.f}, acc1 = {0.f, 0.f, 0.f, 0.f};
#pragma unroll
        for (int s = 0; s < 8; s += 2) {
            acc0 = __builtin_amdgcn_mfma_f32_16x16x32_bf16(a[s],     bb[cur][s],     acc0, 0, 0, 0);
            acc1 = __builtin_amdgcn_mfma_f32_16x16x32_bf16(a[s + 1], bb[cur][s + 1], acc1, 0, 0, 0);
        }
        int node = n0 + t * 16 + lr;
        bool ok = node < N;
        float sn = snv[cur];
        float xr[4];
#pragma unroll
        for (int r = 0; r < 4; ++r) {
            float val = (acc0[r] + acc1[r] + b2a[r]) * sn;
            val = ok ? val : 0.f;
            xr[r] = val;
            s1[r] += val;
            s2[r] = fmaf(val, val, s2[r]);
        }
        *(float4*)(h2 + (size_t)node * 64 + w * 16 + lg * 4) =
            make_float4(xr[0], xr[1], xr[2], xr[3]);
    }
#undef LOADT

#pragma unroll
    for (int m = 1; m < 16; m <<= 1) {
#pragma unroll
        for (int r = 0; r < 4; ++r) {
            s1[r] += __shfl_xor(s1[r], m);
            s2[r] += __shfl_xor(s2[r], m);
        }
    }
    if (lr == 0) {
        int d = w * 16 + lg * 4;
        float* bp = bn_part + (size_t)blockIdx.x * 128;
#pragma unroll
        for (int r = 0; r < 4; ++r) {
            bp[d + r]      = s1[r];
            bp[64 + d + r] = s2[r];
        }
    }
}

// ---------------- K6b: parallel reduce of BN partials -> scale/bias ----------------
__global__ __launch_bounds__(1024) void bn_reduce_kernel(
    const float* __restrict__ bn_part, const float* __restrict__ gamma,
    const float* __restrict__ beta, float* __restrict__ bn_buf, int nblk, float invN)
{
    __shared__ float sred[1024];
    int t = threadIdx.x;
    int d = t & 127;
    int sl = t >> 7;
    float s = 0.f;
    for (int b = sl; b < nblk; b += 8)
        s += bn_part[(size_t)b * 128 + d];
    sred[t] = s;
    __syncthreads();
    if (sl == 0) {
        float tot = s;
#pragma unroll
        for (int k = 1; k < 8; ++k) tot += sred[k * 128 + d];
        sred[d] = tot;
    }
    __syncthreads();
    if (t < 64) {
        float s1 = sred[t], s2 = sred[64 + t];
        float mu = s1 * invN;
        float var = s2 * invN - mu * mu;
        float rstd = rsqrtf(var + 1e-5f);
        float sc = rstd * gamma[t];
        bn_buf[t]      = sc;
        bn_buf[64 + t] = beta[t] - mu * sc;
    }
}

// ---------------- K7: BN normalize + relu + residual ----------------
__global__ __launch_bounds__(256) void bn_final_kernel(
    const float* __restrict__ h, const float* __restrict__ h2,
    const float* __restrict__ bn_buf, float* __restrict__ out, int N)
{
    int idx = blockIdx.x * 256 + threadIdx.x;
    int total4 = N * 16;
    if (idx >= total4) return;
    int base = idx * 4;
    int d0 = base & 63;
    const float4 a = *(const float4*)(h2 + base);
    const float4 hh = *(const float4*)(h + base);
    float r[4] = {a.x, a.y, a.z, a.w};
    float hv[4] = {hh.x, hh.y, hh.z, hh.w};
    float o[4];
#pragma unroll
    for (int k = 0; k < 4; ++k) {
        int d = d0 + k;
        float x = fmaf(r[k], bn_buf[d], bn_buf[64 + d]);
        o[k] = hv[k] + fmaxf(x, 0.f);
    }
    float4 ov = {o[0], o[1], o[2], o[3]};
    *(float4*)(out + base) = ov;
}

// ---------------- launch ----------------
extern "C" void kernel_launch(void* const* d_in, const int* in_sizes, int n_in,
                              void* d_out, int out_size, void* d_ws, size_t ws_size,
                              hipStream_t stream)
{
    const float* h     = (const float*)d_in[0];
    const float* eig   = (const float*)d_in[1];
    const float* snorm = (const float*)d_in[2];
    const int*   src   = (const int*)d_in[3];
    const int*   dst   = (const int*)d_in[4];
    const float* W1    = (const float*)d_in[5];
    const float* b1    = (const float*)d_in[6];
    const float* W2    = (const float*)d_in[7];
    const float* b2    = (const float*)d_in[8];
    const float* gamma = (const float*)d_in[9];
    const float* beta  = (const float*)d_in[10];
    float* out = (float*)d_out;

    const int N = in_sizes[2];
    const int E = in_sizes[1];
    const int Npad = (N + 255) & ~255;   // padded rows: branchless MFMA kernels
    const int pblk = (N + 127) / 128;    // post_mfma grid

    // ---- workspace layout (256B aligned slices) ----
    char* w = (char*)d_ws;
    size_t off = 0;
    auto alloc = [&](size_t bytes) -> char* {
        char* p = w + off;
        off += (bytes + 255) & ~size_t(255);
        return p;
    };
    unsigned short* u = (unsigned short*)alloc((size_t)Npad * 64 * 2);
    unsigned short* v = (unsigned short*)alloc((size_t)Npad * 64 * 2);
    float* h2 = (float*)u;   // alias: u,v dead after agg_kernel
    unsigned short* agg = (unsigned short*)alloc((size_t)Npad * 192 * 2);
    unsigned short* hb  = (unsigned short*)alloc((size_t)Npad * 64 * 2);
    int2* csr = (int2*)alloc((size_t)E * 8);
    int*  rank = (int*)alloc((size_t)E * 4);
    // zero region: cursor (deg histogram) only
    char* zero_base = w + off;
    int*   cursor = (int*)alloc((size_t)N * 4);   // becomes deg
    size_t zero_bytes = (size_t)((w + off) - zero_base);
    float* bn_part = (float*)alloc((size_t)pblk * 128 * 4);
    float* bn_buf  = (float*)alloc(128 * 4);
    int* offs = (int*)alloc((size_t)N * 4);
    int nb = (N + 255) / 256;
    int* bsum  = (int*)alloc((size_t)nb * 4);
    int* bscan = (int*)alloc((size_t)nb * 4);
    unsigned short* w1bf = (unsigned short*)alloc(128 * 64 * 2);
    unsigned short* w2bf = (unsigned short*)alloc(64 * 256 * 2);
    (void)ws_size; (void)n_in; (void)out_size;

    hipMemsetAsync(zero_base, 0, zero_bytes, stream);

    // MEGA1: edge_rank (atomic wall) || hb_cast || wprep
    long total8 = (long)N * 8;
    int nrank = (E + 2047) / 2048;                  // 8 edges/thread
    int ncast = (int)((total8 + 255) / 256);
    int nwprep = (128 * 64 + 64 * 256 + 255) / 256;
    mega1_kernel<<<nrank + ncast + nwprep, 256, 0, stream>>>(
        dst, cursor, rank, E, h, hb, total8, W1, W2, w1bf, w2bf, nrank, ncast);

    block_reduce_kernel<<<nb, 256, 0, stream>>>(cursor, bsum, N);
    scan_bsums_kernel<<<1, 1024, 0, stream>>>(bsum, bscan, nb);
    block_scan_kernel<<<nb, 256, 0, stream>>>(cursor, bscan, offs, N);

    // MEGA2: uv_mfma || csr_scatter
    int nuv = (N + 63) / 64;
    int nscat = (E + 255) / 256;
    mega2_kernel<<<nuv + nscat, 256, 0, stream>>>(
        hb, w1bf, b1, u, v, src, dst, eig, rank, offs, csr, E, nuv);

    int agrid = (int)(((size_t)N * 64 + 255) / 256);
    agg_kernel<<<agrid, 256, 0, stream>>>(u, v, hb, offs, cursor, csr, agg, N);

    post_mfma_kernel<<<pblk, 256, 0, stream>>>(hb, agg, w2bf, b2, snorm,
                                               h2, bn_part, N);

    bn_reduce_kernel<<<1, 1024, 0, stream>>>(bn_part, gamma, beta, bn_buf, pblk, 1.0f / (float)N);

    int fgrid = (N * 16 + 255) / 256;
    bn_final_kernel<<<fgrid, 256, 0, stream>>>(h, h2, bn_buf, out, N);
}

// Round 14
// 314.762 us; speedup vs baseline: 1.1311x; 1.0176x over previous
//
#include <hip/hip_runtime.h>
#include <math.h>

__device__ __forceinline__ float bf2f(unsigned short s) {
    return __uint_as_float(((unsigned)s) << 16);
}
__device__ __forceinline__ unsigned short f2bf(float f) {
    unsigned u = __float_as_uint(f);
    unsigned r = (u + 0x7fffu + ((u >> 16) & 1u)) >> 16;   // RNE
    return (unsigned short)r;
}

typedef __attribute__((ext_vector_type(8))) short short8v;  // 8 bf16 = 4 VGPRs
typedef __attribute__((ext_vector_type(4))) float f32x4;

// ================= device bodies (shared by mega kernels) =================

// ---- rank + deg histogram: 8 edges/thread, 8 atomic-returns in flight ----
// ~24G scattered device-atomics/s is a HW wall (1-wide, 8-wide ILP, 8x-striped
// all ~52-54us). We hide independent streaming work under it instead.
__device__ __forceinline__ void edge_rank_body(
    int bid, const int* __restrict__ dst, int* __restrict__ cursor,
    int* __restrict__ rank, int E)
{
    int t = bid * 256 + threadIdx.x;
    int base = t * 8;
    if (base >= E) return;
    if (base + 8 <= E) {
        int4 d0 = *(const int4*)(dst + base);
        int4 d1 = *(const int4*)(dst + base + 4);
        int r0 = atomicAdd(&cursor[d0.x], 1);
        int r1 = atomicAdd(&cursor[d0.y], 1);
        int r2 = atomicAdd(&cursor[d0.z], 1);
        int r3 = atomicAdd(&cursor[d0.w], 1);
        int r4 = atomicAdd(&cursor[d1.x], 1);
        int r5 = atomicAdd(&cursor[d1.y], 1);
        int r6 = atomicAdd(&cursor[d1.z], 1);
        int r7 = atomicAdd(&cursor[d1.w], 1);
        *(int4*)(rank + base)     = make_int4(r0, r1, r2, r3);
        *(int4*)(rank + base + 4) = make_int4(r4, r5, r6, r7);
    } else {
        for (int e = base; e < E; ++e)
            rank[e] = atomicAdd(&cursor[dst[e]], 1);
    }
}

// ---- h (fp32) -> hb (bf16), vectorized cast ----
__device__ __forceinline__ void hb_cast_body(
    int bid, const float* __restrict__ h, unsigned short* __restrict__ hb, long total8)
{
    long idx = (long)bid * 256 + threadIdx.x;
    if (idx >= total8) return;
    const float4 a = *(const float4*)(h + idx * 8);
    const float4 b = *(const float4*)(h + idx * 8 + 4);
    union { unsigned short s[8]; uint4 v4; } pk;
    pk.s[0] = f2bf(a.x); pk.s[1] = f2bf(a.y); pk.s[2] = f2bf(a.z); pk.s[3] = f2bf(a.w);
    pk.s[4] = f2bf(b.x); pk.s[5] = f2bf(b.y); pk.s[6] = f2bf(b.z); pk.s[7] = f2bf(b.w);
    *(uint4*)(hb + idx * 8) = pk.v4;
}

// ---- weight prep -> bf16 (tiny; rides MEGA1 tail) ----
__device__ __forceinline__ void wprep_body(
    int bid, const float* __restrict__ W1, const float* __restrict__ W2,
    unsigned short* __restrict__ w1bf, unsigned short* __restrict__ w2bf)
{
    int idx = bid * 256 + threadIdx.x;
    if (idx < 128 * 64) {
        int c = idx >> 6, j = idx & 63;
        float val = (c < 64) ? W1[c * 128 + j] : W1[(c - 64) * 128 + 64 + j];
        w1bf[idx] = f2bf(val);
    } else if (idx < 128 * 64 + 64 * 256) {
        int k = idx - 128 * 64;
        w2bf[k] = f2bf(W2[k]);
    }
}

// ---- scatter edges into CSR (no atomics, packed 8B) ----
__device__ __forceinline__ void csr_scatter_body(
    int bid, const int* __restrict__ src, const int* __restrict__ dst,
    const float* __restrict__ eig, const int* __restrict__ rank,
    const int* __restrict__ offs, int2* __restrict__ csr, int E)
{
    int e = bid * 256 + threadIdx.x;
    if (e < E) {
        int dn = dst[e];
        int p = offs[dn] + rank[e];
        csr[p] = make_int2(src[e], __float_as_int(eig[e]));
    }
}

// ---- u,v via MFMA (branchless, prefetch double-buffer) ----
__device__ __forceinline__ void uv_mfma_body(
    int bid, const unsigned short* __restrict__ hb, const unsigned short* __restrict__ w1bf,
    const float* __restrict__ b1,
    unsigned short* __restrict__ u, unsigned short* __restrict__ v)
{
    int lane = threadIdx.x & 63;
    int wv = threadIdx.x >> 6;          // c-block: c = wv*32 .. wv*32+31
    int lr = lane & 15;
    int lg = lane >> 4;

    short8v a[2][2];
#pragma unroll
    for (int rt = 0; rt < 2; ++rt)
#pragma unroll
        for (int s = 0; s < 2; ++s)
            a[rt][s] = *(const short8v*)(w1bf + (size_t)(wv * 32 + rt * 16 + lr) * 64 + s * 32 + lg * 8);

    float b1v[2][4];
#pragma unroll
    for (int rt = 0; rt < 2; ++rt) {
        if (wv >= 2) {
            float4 t4 = *(const float4*)(b1 + (wv - 2) * 32 + rt * 16 + lg * 4);
            b1v[rt][0] = t4.x; b1v[rt][1] = t4.y; b1v[rt][2] = t4.z; b1v[rt][3] = t4.w;
        } else {
            b1v[rt][0] = b1v[rt][1] = b1v[rt][2] = b1v[rt][3] = 0.f;
        }
    }

    unsigned short* outp = (wv < 2) ? u : v;
    int coff0 = (wv & 1) * 32 + lg * 4;

    int n0 = bid * 64;

    short8v bb[2][2];
    {
        const unsigned short* hp = hb + (size_t)(n0 + lr) * 64 + lg * 8;
        bb[0][0] = *(const short8v*)(hp);
        bb[0][1] = *(const short8v*)(hp + 32);
    }
#pragma unroll
    for (int t = 0; t < 4; ++t) {
        int cur = t & 1, nxt = cur ^ 1;
        if (t < 3) {
            const unsigned short* hp = hb + (size_t)(n0 + (t + 1) * 16 + lr) * 64 + lg * 8;
            bb[nxt][0] = *(const short8v*)(hp);
            bb[nxt][1] = *(const short8v*)(hp + 32);
        }
        f32x4 acc0 = {0.f, 0.f, 0.f, 0.f}, acc1 = {0.f, 0.f, 0.f, 0.f};
        acc0 = __builtin_amdgcn_mfma_f32_16x16x32_bf16(a[0][0], bb[cur][0], acc0, 0, 0, 0);
        acc1 = __builtin_amdgcn_mfma_f32_16x16x32_bf16(a[1][0], bb[cur][0], acc1, 0, 0, 0);
        acc0 = __builtin_amdgcn_mfma_f32_16x16x32_bf16(a[0][1], bb[cur][1], acc0, 0, 0, 0);
        acc1 = __builtin_amdgcn_mfma_f32_16x16x32_bf16(a[1][1], bb[cur][1], acc1, 0, 0, 0);
        int node = n0 + t * 16 + lr;
        union { unsigned short s[4]; uint2 v2; } pk;
#pragma unroll
        for (int r = 0; r < 4; ++r) pk.s[r] = f2bf(acc0[r] + b1v[0][r]);
        *(uint2*)(outp + (size_t)node * 64 + coff0) = pk.v2;
#pragma unroll
        for (int r = 0; r < 4; ++r) pk.s[r] = f2bf(acc1[r] + b1v[1][r]);
        *(uint2*)(outp + (size_t)node * 64 + coff0 + 16) = pk.v2;
    }
}

// ================= MEGA kernels: overlap independent stages =================
__global__ __launch_bounds__(256) void mega1_kernel(
    const int* __restrict__ dst, int* __restrict__ cursor, int* __restrict__ rank, int E,
    const float* __restrict__ h, unsigned short* __restrict__ hb, long total8,
    const float* __restrict__ W1, const float* __restrict__ W2,
    unsigned short* __restrict__ w1bf, unsigned short* __restrict__ w2bf,
    int nrank, int ncast)
{
    int b = blockIdx.x;
    if (b < nrank)              edge_rank_body(b, dst, cursor, rank, E);
    else if (b < nrank + ncast) hb_cast_body(b - nrank, h, hb, total8);
    else                        wprep_body(b - nrank - ncast, W1, W2, w1bf, w2bf);
}

__global__ __launch_bounds__(256) void mega2_kernel(
    const unsigned short* __restrict__ hb, const unsigned short* __restrict__ w1bf,
    const float* __restrict__ b1, unsigned short* __restrict__ u, unsigned short* __restrict__ v,
    const int* __restrict__ src, const int* __restrict__ dst, const float* __restrict__ eig,
    const int* __restrict__ rank, const int* __restrict__ offs, int2* __restrict__ csr,
    int E, int nuv)
{
    int b = blockIdx.x;
    if (b < nuv) uv_mfma_body(b, hb, w1bf, b1, u, v);
    else         csr_scatter_body(b - nuv, src, dst, eig, rank, offs, csr, E);
}

// ---------------- K2a: per-block reduce of deg ----------------
__global__ __launch_bounds__(256) void block_reduce_kernel(
    const int* __restrict__ deg, int* __restrict__ bsum, int N)
{
    __shared__ int sd[256];
    int t = threadIdx.x;
    int i = blockIdx.x * 256 + t;
    sd[t] = (i < N) ? deg[i] : 0;
    __syncthreads();
    for (int s = 128; s > 0; s >>= 1) {
        if (t < s) sd[t] += sd[t + s];
        __syncthreads();
    }
    if (t == 0) bsum[blockIdx.x] = sd[0];
}

// ---------------- K2b: scan block sums (single block) ----------------
__global__ __launch_bounds__(1024) void scan_bsums_kernel(
    const int* __restrict__ bsum, int* __restrict__ bscan, int nb)
{
    __shared__ int sd[1024];
    int t = threadIdx.x;
    int own = (t < nb) ? bsum[t] : 0;
    sd[t] = own;
    __syncthreads();
    for (int off = 1; off < 1024; off <<= 1) {
        int v = (t >= off) ? sd[t - off] : 0;
        __syncthreads();
        sd[t] += v;
        __syncthreads();
    }
    if (t < nb) bscan[t] = sd[t] - own;   // exclusive prefix
}

// ---------------- K2c: per-block exclusive scan -> offsets ----------------
__global__ __launch_bounds__(256) void block_scan_kernel(
    const int* __restrict__ deg, const int* __restrict__ bscan,
    int* __restrict__ offs, int N)
{
    __shared__ int sd[256];
    int t = threadIdx.x;
    int i = blockIdx.x * 256 + t;
    int myv = (i < N) ? deg[i] : 0;
    sd[t] = myv;
    __syncthreads();
    for (int off = 1; off < 256; off <<= 1) {
        int v = (t >= off) ? sd[t - off] : 0;
        __syncthreads();
        sd[t] += v;
        __syncthreads();
    }
    if (i < N) {
        offs[i] = sd[t] - myv + bscan[blockIdx.x];
    }
}

// ---------------- K5: aggregation, one wave per node (scalar edge records) ----------------
__global__ __launch_bounds__(256) void agg_kernel(
    const unsigned short* __restrict__ u, const unsigned short* __restrict__ v,
    const unsigned short* __restrict__ hb,
    const int* __restrict__ offs, const int* __restrict__ degi,
    const int2* __restrict__ csr,
    unsigned short* __restrict__ agg, int N)
{
    int gw = (blockIdx.x * 256 + threadIdx.x) >> 6;
    int lane = threadIdx.x & 63;
    int n = __builtin_amdgcn_readfirstlane(gw);
    if (n >= N) return;
    int dn  = __builtin_amdgcn_readfirstlane(degi[n]);
    int beg = __builtin_amdgcn_readfirstlane(offs[n]);

    float vl = bf2f(v[(size_t)n * 64 + lane]);
    float hl = bf2f(hb[(size_t)n * 64 + lane]);

    const int2* ep = csr + beg;
    float accs = 0.f, accd = 0.f, accm = -3.402823466e38f;
    float pa = 0.f, ps = 0.f;

    int j = 0;
    for (; j + 4 <= dn; j += 4) {
        int2 r0 = ep[j], r1 = ep[j + 1], r2 = ep[j + 2], r3 = ep[j + 3];
        float u0 = bf2f(u[(size_t)r0.x * 64 + lane]);
        float u1 = bf2f(u[(size_t)r1.x * 64 + lane]);
        float u2 = bf2f(u[(size_t)r2.x * 64 + lane]);
        float u3 = bf2f(u[(size_t)r3.x * 64 + lane]);
        float w0 = __int_as_float(r0.y), w1 = __int_as_float(r1.y);
        float w2_ = __int_as_float(r2.y), w3 = __int_as_float(r3.y);
        pa += (fabsf(w0) + fabsf(w1)) + (fabsf(w2_) + fabsf(w3));
        ps += (w0 + w1) + (w2_ + w3);
        accs += (u0 + u1) + (u2 + u3);
        accm = fmaxf(accm, fmaxf(fmaxf(u0, u1), fmaxf(u2, u3)));
        accd = fmaf(w0, u0, fmaf(w1, u1, fmaf(w2_, u2, fmaf(w3, u3, accd))));
    }
    for (; j < dn; ++j) {
        int2 r0 = ep[j];
        float u0 = bf2f(u[(size_t)r0.x * 64 + lane]);
        float w0 = __int_as_float(r0.y);
        pa += fabsf(w0);
        ps += w0;
        accs += u0;
        accm = fmaxf(accm, u0);
        accd = fmaf(w0, u0, accd);
    }

    float inv_ab = 1.f / (pa + 1e-8f);
    float segw = ps * inv_ab;

    float fdeg = (float)dn;
    float mean = (accs + fdeg * vl) / fmaxf(fdeg, 1.f);
    float amax = (dn > 0) ? (accm + vl) : 0.f;
    float adir = fabsf(fmaf(accd, inv_ab, segw * (vl - hl)));
    size_t base = (size_t)n * 192;
    agg[base + lane]       = f2bf(mean);
    agg[base + 64 + lane]  = f2bf(amax);
    agg[base + 128 + lane] = f2bf(adir);
}

// ---------------- K6: posttrans via MFMA + per-block BN partials (NO atomics) ----------------
// 128 nodes/block (8 tiles), 4 waves split over d; bf16 w2bf (L2-hot, minimal bytes).
__global__ __launch_bounds__(256) void post_mfma_kernel(
    const unsigned short* __restrict__ hb, const unsigned short* __restrict__ agg,
    const unsigned short* __restrict__ w2bf, const float* __restrict__ b2,
    const float* __restrict__ snorm, float* __restrict__ h2,
    float* __restrict__ bn_part, int N)
{
    int lane = threadIdx.x & 63;
    int w = threadIdx.x >> 6;
    int lr = lane & 15;
    int lg = lane >> 4;

    short8v a[8];
    {
        const unsigned short* ab = w2bf + ((size_t)(w * 16 + lr)) * 256 + lg * 8;
#pragma unroll
        for (int s = 0; s < 8; ++s)
            a[s] = *(const short8v*)(ab + s * 32);
    }
    float4 b2v = *(const float4*)(b2 + w * 16 + lg * 4);
    float b2a[4] = {b2v.x, b2v.y, b2v.z, b2v.w};

    int n0 = blockIdx.x * 128;
    float s1[4] = {0.f, 0.f, 0.f, 0.f}, s2[4] = {0.f, 0.f, 0.f, 0.f};

    short8v bb[2][8];
    float snv[2];

#define LOADT(BUF, T)                                                            \
    {                                                                            \
        int node_ = n0 + (T) * 16 + lr;                                          \
        const unsigned short* hbp_ = hb  + (size_t)node_ * 64  + lg * 8;         \
        const unsigned short* agp_ = agg + (size_t)node_ * 192 + lg * 8;         \
        bb[BUF][0] = *(const short8v*)(hbp_);                                    \
        bb[BUF][1] = *(const short8v*)(hbp_ + 32);                               \
        bb[BUF][2] = *(const short8v*)(agp_);                                    \
        bb[BUF][3] = *(const short8v*)(agp_ + 32);                               \
        bb[BUF][4] = *(const short8v*)(agp_ + 64);                               \
        bb[BUF][5] = *(const short8v*)(agp_ + 96);                               \
        bb[BUF][6] = *(const short8v*)(agp_ + 128);                              \
        bb[BUF][7] = *(const short8v*)(agp_ + 160);                              \
        int nc_ = (node_ < N) ? node_ : (N - 1);                                 \
        snv[BUF] = snorm[nc_];                                                   \
    }

    LOADT(0, 0)
#pragma unroll
    for (int t = 0; t < 8; ++t) {
        int cur = t & 1, nxt = cur ^ 1;
        if (t < 7) LOADT(nxt, t + 1)
        f32x4 acc0 = {0.f, 0.f, 0.f, 0.f}, acc1 = {0.f, 0.f, 0.f, 0.f};
#pragma unroll
        for (int s = 0; s < 8; s += 2) {
            acc0 = __builtin_amdgcn_mfma_f32_16x16x32_bf16(a[s],     bb[cur][s],     acc0, 0, 0, 0);
            acc1 = __builtin_amdgcn_mfma_f32_16x16x32_bf16(a[s + 1], bb[cur][s + 1], acc1, 0, 0, 0);
        }
        int node = n0 + t * 16 + lr;
        bool ok = node < N;
        float sn = snv[cur];
        float xr[4];
#pragma unroll
        for (int r = 0; r < 4; ++r) {
            float val = (acc0[r] + acc1[r] + b2a[r]) * sn;
            val = ok ? val : 0.f;
            xr[r] = val;
            s1[r] += val;
            s2[r] = fmaf(val, val, s2[r]);
        }
        *(float4*)(h2 + (size_t)node * 64 + w * 16 + lg * 4) =
            make_float4(xr[0], xr[1], xr[2], xr[3]);
    }
#undef LOADT

#pragma unroll
    for (int m = 1; m < 16; m <<= 1) {
#pragma unroll
        for (int r = 0; r < 4; ++r) {
            s1[r] += __shfl_xor(s1[r], m);
            s2[r] += __shfl_xor(s2[r], m);
        }
    }
    if (lr == 0) {
        int d = w * 16 + lg * 4;
        float* bp = bn_part + (size_t)blockIdx.x * 128;
#pragma unroll
        for (int r = 0; r < 4; ++r) {
            bp[d + r]      = s1[r];
            bp[64 + d + r] = s2[r];
        }
    }
}

// ---------------- K6b: parallel reduce of BN partials -> scale/bias ----------------
__global__ __launch_bounds__(1024) void bn_reduce_kernel(
    const float* __restrict__ bn_part, const float* __restrict__ gamma,
    const float* __restrict__ beta, float* __restrict__ bn_buf, int nblk, float invN)
{
    __shared__ float sred[1024];
    int t = threadIdx.x;
    int d = t & 127;
    int sl = t >> 7;
    float s = 0.f;
    for (int b = sl; b < nblk; b += 8)
        s += bn_part[(size_t)b * 128 + d];
    sred[t] = s;
    __syncthreads();
    if (sl == 0) {
        float tot = s;
#pragma unroll
        for (int k = 1; k < 8; ++k) tot += sred[k * 128 + d];
        sred[d] = tot;
    }
    __syncthreads();
    if (t < 64) {
        float s1 = sred[t], s2 = sred[64 + t];
        float mu = s1 * invN;
        float var = s2 * invN - mu * mu;
        float rstd = rsqrtf(var + 1e-5f);
        float sc = rstd * gamma[t];
        bn_buf[t]      = sc;
        bn_buf[64 + t] = beta[t] - mu * sc;
    }
}

// ---------------- K7: BN normalize + relu + residual ----------------
__global__ __launch_bounds__(256) void bn_final_kernel(
    const float* __restrict__ h, const float* __restrict__ h2,
    const float* __restrict__ bn_buf, float* __restrict__ out, int N)
{
    int idx = blockIdx.x * 256 + threadIdx.x;
    int total4 = N * 16;
    if (idx >= total4) return;
    int base = idx * 4;
    int d0 = base & 63;
    const float4 a = *(const float4*)(h2 + base);
    const float4 hh = *(const float4*)(h + base);
    float r[4] = {a.x, a.y, a.z, a.w};
    float hv[4] = {hh.x, hh.y, hh.z, hh.w};
    float o[4];
#pragma unroll
    for (int k = 0; k < 4; ++k) {
        int d = d0 + k;
        float x = fmaf(r[k], bn_buf[d], bn_buf[64 + d]);
        o[k] = hv[k] + fmaxf(x, 0.f);
    }
    float4 ov = {o[0], o[1], o[2], o[3]};
    *(float4*)(out + base) = ov;
}

// ---------------- launch ----------------
extern "C" void kernel_launch(void* const* d_in, const int* in_sizes, int n_in,
                              void* d_out, int out_size, void* d_ws, size_t ws_size,
                              hipStream_t stream)
{
    const float* h     = (const float*)d_in[0];
    const float* eig   = (const float*)d_in[1];
    const float* snorm = (const float*)d_in[2];
    const int*   src   = (const int*)d_in[3];
    const int*   dst   = (const int*)d_in[4];
    const float* W1    = (const float*)d_in[5];
    const float* b1    = (const float*)d_in[6];
    const float* W2    = (const float*)d_in[7];
    const float* b2    = (const float*)d_in[8];
    const float* gamma = (const float*)d_in[9];
    const float* beta  = (const float*)d_in[10];
    float* out = (float*)d_out;

    const int N = in_sizes[2];
    const int E = in_sizes[1];
    const int Npad = (N + 255) & ~255;   // padded rows: branchless MFMA kernels
    const int pblk = (N + 127) / 128;    // post_mfma grid

    // ---- workspace layout (256B aligned slices) ----
    char* w = (char*)d_ws;
    size_t off = 0;
    auto alloc = [&](size_t bytes) -> char* {
        char* p = w + off;
        off += (bytes + 255) & ~size_t(255);
        return p;
    };
    unsigned short* u = (unsigned short*)alloc((size_t)Npad * 64 * 2);
    unsigned short* v = (unsigned short*)alloc((size_t)Npad * 64 * 2);
    float* h2 = (float*)u;   // alias: u,v dead after agg_kernel
    unsigned short* agg = (unsigned short*)alloc((size_t)Npad * 192 * 2);
    unsigned short* hb  = (unsigned short*)alloc((size_t)Npad * 64 * 2);
    int2* csr = (int2*)alloc((size_t)E * 8);
    int*  rank = (int*)alloc((size_t)E * 4);
    // zero region: cursor (deg histogram) only
    char* zero_base = w + off;
    int*   cursor = (int*)alloc((size_t)N * 4);   // becomes deg
    size_t zero_bytes = (size_t)((w + off) - zero_base);
    float* bn_part = (float*)alloc((size_t)pblk * 128 * 4);
    float* bn_buf  = (float*)alloc(128 * 4);
    int* offs = (int*)alloc((size_t)N * 4);
    int nb = (N + 255) / 256;
    int* bsum  = (int*)alloc((size_t)nb * 4);
    int* bscan = (int*)alloc((size_t)nb * 4);
    unsigned short* w1bf = (unsigned short*)alloc(128 * 64 * 2);
    unsigned short* w2bf = (unsigned short*)alloc(64 * 256 * 2);
    (void)ws_size; (void)n_in; (void)out_size;

    hipMemsetAsync(zero_base, 0, zero_bytes, stream);

    // MEGA1: edge_rank (atomic wall) || hb_cast || wprep
    long total8 = (long)N * 8;
    int nrank = (E + 2047) / 2048;                  // 8 edges/thread
    int ncast = (int)((total8 + 255) / 256);
    int nwprep = (128 * 64 + 64 * 256 + 255) / 256;
    mega1_kernel<<<nrank + ncast + nwprep, 256, 0, stream>>>(
        dst, cursor, rank, E, h, hb, total8, W1, W2, w1bf, w2bf, nrank, ncast);

    block_reduce_kernel<<<nb, 256, 0, stream>>>(cursor, bsum, N);
    scan_bsums_kernel<<<1, 1024, 0, stream>>>(bsum, bscan, nb);
    block_scan_kernel<<<nb, 256, 0, stream>>>(cursor, bscan, offs, N);

    // MEGA2: uv_mfma || csr_scatter
    int nuv = (N + 63) / 64;
    int nscat = (E + 255) / 256;
    mega2_kernel<<<nuv + nscat, 256, 0, stream>>>(
        hb, w1bf, b1, u, v, src, dst, eig, rank, offs, csr, E, nuv);

    int agrid = (int)(((size_t)N * 64 + 255) / 256);
    agg_kernel<<<agrid, 256, 0, stream>>>(u, v, hb, offs, cursor, csr, agg, N);

    post_mfma_kernel<<<pblk, 256, 0, stream>>>(hb, agg, w2bf, b2, snorm,
                                               h2, bn_part, N);

    bn_reduce_kernel<<<1, 1024, 0, stream>>>(bn_part, gamma, beta, bn_buf, pblk, 1.0f / (float)N);

    int fgrid = (N * 16 + 255) / 256;
    bn_final_kernel<<<fgrid, 256, 0, stream>>>(h, h2, bn_buf, out, N);
}